// Round 1
// baseline (766.977 us; speedup 1.0000x reference)
//
#include <hip/hip_runtime.h>
#include <hip/hip_bf16.h>
#include <math.h>

// Problem constants
#define BB 8
#define LL 1024
#define DD 1024
#define FF 4096
#define NHH 8
#define HSS 128
#define SCALE 0.08838834764831845f  // 1/sqrt(128)

typedef __bf16 bf16;
typedef __bf16 bf16x8 __attribute__((ext_vector_type(8)));
typedef float f32x4 __attribute__((ext_vector_type(4)));

__device__ inline void async_copy16(const void* g, void* l) {
  __builtin_amdgcn_global_load_lds(
      (const __attribute__((address_space(1))) unsigned int*)g,
      (__attribute__((address_space(3))) unsigned int*)l, 16, 0, 0);
}

// ---------------------------------------------------------------------------
// Transpose + cast: W [K][N] fp32 -> Wt [N][K] bf16
// ---------------------------------------------------------------------------
__global__ __launch_bounds__(256)
void transpose_cast_kernel(const float* __restrict__ W, bf16* __restrict__ Wt,
                           int K, int N) {
  __shared__ float tile[32][33];
  int n0 = blockIdx.x * 32, k0 = blockIdx.y * 32;
  int tx = threadIdx.x, ty = threadIdx.y;
#pragma unroll
  for (int i = 0; i < 32; i += 8)
    tile[ty + i][tx] = W[(size_t)(k0 + ty + i) * N + n0 + tx];
  __syncthreads();
#pragma unroll
  for (int i = 0; i < 32; i += 8)
    Wt[(size_t)(n0 + ty + i) * K + k0 + tx] = (bf16)tile[tx][ty + i];
}

__global__ __launch_bounds__(256)
void cast_bf16_kernel(const float* __restrict__ src, bf16* __restrict__ dst, int n) {
  int i = blockIdx.x * blockDim.x + threadIdx.x;
  if (i < n) dst[i] = (bf16)src[i];
}

// ---------------------------------------------------------------------------
// LayerNorm: x [8192][1024] fp32 -> out bf16
// ---------------------------------------------------------------------------
__global__ __launch_bounds__(256)
void ln_kernel(const float* __restrict__ x, const float* __restrict__ g,
               const float* __restrict__ bta, bf16* __restrict__ out) {
  int row = blockIdx.x;
  int tid = threadIdx.x;
  const float4 v = ((const float4*)(x + (size_t)row * DD))[tid];
  float s = v.x + v.y + v.z + v.w;
  float s2 = v.x * v.x + v.y * v.y + v.z * v.z + v.w * v.w;
#pragma unroll
  for (int o = 32; o > 0; o >>= 1) {
    s += __shfl_down(s, o);
    s2 += __shfl_down(s2, o);
  }
  __shared__ float a1[4], a2[4];
  int wave = tid >> 6;
  if ((tid & 63) == 0) { a1[wave] = s; a2[wave] = s2; }
  __syncthreads();
  s = a1[0] + a1[1] + a1[2] + a1[3];
  s2 = a2[0] + a2[1] + a2[2] + a2[3];
  float mu = s * (1.0f / DD);
  float rstd = rsqrtf(s2 * (1.0f / DD) - mu * mu + 1e-5f);
  float4 gv = ((const float4*)g)[tid];
  float4 bv = ((const float4*)bta)[tid];
  bf16* o4 = out + (size_t)row * DD + tid * 4;
  o4[0] = (bf16)((v.x - mu) * rstd * gv.x + bv.x);
  o4[1] = (bf16)((v.y - mu) * rstd * gv.y + bv.y);
  o4[2] = (bf16)((v.z - mu) * rstd * gv.z + bv.z);
  o4[3] = (bf16)((v.w - mu) * rstd * gv.w + bv.w);
}

// ---------------------------------------------------------------------------
// GEMM: C[M][N] = A[M][K](bf16) * Bt[N][K](bf16)^T + bias
// EPI 0: -> bf16   EPI 1: gelu -> bf16   EPI 2: + res(fp32) -> fp32
// 128x128 tile, BK=32, 4 waves each 64x64 via 4x4 mfma_16x16x32_bf16
// ---------------------------------------------------------------------------
template <int EPI>
__global__ __launch_bounds__(256)
void gemm_kernel(const bf16* __restrict__ A, const bf16* __restrict__ Bt,
                 const float* __restrict__ bias, const float* __restrict__ res,
                 void* __restrict__ Cout, int M, int N, int K) {
  __shared__ bf16 Als[128 * 32];
  __shared__ bf16 Bls[128 * 32];
  int tid = threadIdx.x;
  int wave = tid >> 6, lane = tid & 63;
  int l15 = lane & 15, quad = lane >> 4;
  int m0 = blockIdx.y * 128, n0 = blockIdx.x * 128;
  int wm = (wave >> 1) * 64, wn = (wave & 1) * 64;
  f32x4 acc[4][4] = {};

  for (int k0 = 0; k0 < K; k0 += 32) {
    __syncthreads();
#pragma unroll
    for (int i = 0; i < 2; i++) {
      int t = i * 256 + tid;
      int row = t >> 2, kc = (t & 3) << 3;
      async_copy16(A + (size_t)(m0 + row) * K + k0 + kc, &Als[t * 8]);
      async_copy16(Bt + (size_t)(n0 + row) * K + k0 + kc, &Bls[t * 8]);
    }
    __syncthreads();
    bf16x8 af[4], bfr[4];
#pragma unroll
    for (int mt = 0; mt < 4; mt++)
      af[mt] = *(const bf16x8*)&Als[(wm + mt * 16 + l15) * 32 + quad * 8];
#pragma unroll
    for (int nt = 0; nt < 4; nt++)
      bfr[nt] = *(const bf16x8*)&Bls[(wn + nt * 16 + l15) * 32 + quad * 8];
#pragma unroll
    for (int mt = 0; mt < 4; mt++)
#pragma unroll
      for (int nt = 0; nt < 4; nt++)
        acc[mt][nt] = __builtin_amdgcn_mfma_f32_16x16x32_bf16(af[mt], bfr[nt],
                                                              acc[mt][nt], 0, 0, 0);
  }

#pragma unroll
  for (int mt = 0; mt < 4; mt++) {
#pragma unroll
    for (int nt = 0; nt < 4; nt++) {
      int col = n0 + wn + nt * 16 + l15;
      float bv = bias[col];
#pragma unroll
      for (int r = 0; r < 4; r++) {
        int row = m0 + wm + mt * 16 + quad * 4 + r;
        float v = acc[mt][nt][r] + bv;
        if (EPI == 1) v = 0.5f * v * (1.0f + erff(v * 0.7071067811865475f));
        if (EPI == 2) {
          v += res[(size_t)row * N + col];
          ((float*)Cout)[(size_t)row * N + col] = v;
        } else {
          ((bf16*)Cout)[(size_t)row * N + col] = (bf16)v;
        }
      }
    }
  }
}

// ---------------------------------------------------------------------------
// Flash attention with relative-position skew bias.
// scores[q,k] = (q.k + q.Er[1023-q+k]) * scale, causal.
// Block: 256 thr (4 waves), each wave owns 16 q rows; BQ=64, BK=64.
// ---------------------------------------------------------------------------
__global__ __launch_bounds__(256)
void flash_kernel(const bf16* __restrict__ qkv, const bf16* __restrict__ Erb,
                  bf16* __restrict__ y) {
  __shared__ bf16 Kls[64][136];     // K tile [k][d], padded rows
  __shared__ bf16 Vls[128][72];     // V^T tile [d][k], padded rows
  __shared__ float Rls[4][16][84];  // per-wave Q.Er^T band
  __shared__ bf16 Pls[4][16][72];   // per-wave P tile in A-frag layout

  int tid = threadIdx.x, wave = tid >> 6, lane = tid & 63;
  int l15 = lane & 15, quad = lane >> 4;
  int qb = blockIdx.x, h = blockIdx.y, b = blockIdx.z;
  int qw0 = qb * 64 + wave * 16;

  const size_t rs = 3 * DD;
  const bf16* qbase = qkv + (size_t)b * LL * rs + h * HSS;
  const bf16* kbase = qbase + DD;
  const bf16* vbase = qbase + 2 * DD;

  // Q fragments (A-operand), row = qw0+l15, contraction d split 4x32
  bf16x8 qf[4];
#pragma unroll
  for (int s = 0; s < 4; s++)
    qf[s] = *(const bf16x8*)(qbase + (size_t)(qw0 + l15) * rs + s * 32 + quad * 8);

  f32x4 o[8] = {};
  float mrow[4] = {-INFINITY, -INFINITY, -INFINITY, -INFINITY};
  float lrow[4] = {0.f, 0.f, 0.f, 0.f};

  int nkt = qb + 1;
  for (int kt = 0; kt < nkt; kt++) {
    int k0 = kt * 64;
    __syncthreads();  // guard LDS reuse
    // stage K tile and transposed V tile
#pragma unroll
    for (int i = 0; i < 4; i++) {
      int c = i * 256 + tid;
      int row = c >> 4, dc = (c & 15) << 3;
      *(bf16x8*)&Kls[row][dc] =
          *(const bf16x8*)(kbase + (size_t)(k0 + row) * rs + dc);
      bf16x8 vv = *(const bf16x8*)(vbase + (size_t)(k0 + row) * rs + dc);
#pragma unroll
      for (int j = 0; j < 8; j++) Vls[dc + j][row] = vv[j];
    }
    __syncthreads();

    // S = Q K^T  (4 n-tiles of 16 k-cols)
    f32x4 sa[4] = {};
#pragma unroll
    for (int nt = 0; nt < 4; nt++)
#pragma unroll
      for (int st = 0; st < 4; st++) {
        bf16x8 kf = *(const bf16x8*)&Kls[nt * 16 + l15][st * 32 + quad * 8];
        sa[nt] = __builtin_amdgcn_mfma_f32_16x16x32_bf16(qf[st], kf, sa[nt], 0, 0, 0);
      }

    // R band = Q @ Er^T, m in [m_base, m_base+80). Only offsets c=15-qloc+koff
    // in [0,78] are consumed for unmasked (k<=q) entries, which always map to
    // valid m in [0,1023]; OOB rows clamp (garbage lands only on masked cells).
    int m_base = 1008 - qw0 + k0;
#pragma unroll
    for (int nt = 0; nt < 5; nt++) {
      int mr = m_base + nt * 16 + l15;
      mr = mr < 0 ? 0 : (mr > 1023 ? 1023 : mr);
      f32x4 rr = {};
#pragma unroll
      for (int st = 0; st < 4; st++) {
        bf16x8 ef = *(const bf16x8*)(Erb + (size_t)mr * HSS + st * 32 + quad * 8);
        rr = __builtin_amdgcn_mfma_f32_16x16x32_bf16(qf[st], ef, rr, 0, 0, 0);
      }
#pragma unroll
      for (int rg = 0; rg < 4; rg++)
        Rls[wave][quad * 4 + rg][nt * 16 + l15] = rr[rg];
    }
    __syncthreads();  // Rls write -> read

    // combine, scale, causal mask; row-max
    float pmx[4] = {-INFINITY, -INFINITY, -INFINITY, -INFINITY};
    float sv[4][4];
#pragma unroll
    for (int nt = 0; nt < 4; nt++) {
      int koff = nt * 16 + l15;
      int kg = k0 + koff;
#pragma unroll
      for (int rg = 0; rg < 4; rg++) {
        int qloc = quad * 4 + rg;
        int qg = qw0 + qloc;
        float v = (sa[nt][rg] + Rls[wave][qloc][15 - qloc + koff]) * SCALE;
        v = (kg <= qg) ? v : -INFINITY;
        sv[nt][rg] = v;
        pmx[rg] = fmaxf(pmx[rg], v);
      }
    }
#pragma unroll
    for (int rg = 0; rg < 4; rg++) {
      float v = pmx[rg];
      v = fmaxf(v, __shfl_xor(v, 1));
      v = fmaxf(v, __shfl_xor(v, 2));
      v = fmaxf(v, __shfl_xor(v, 4));
      v = fmaxf(v, __shfl_xor(v, 8));
      float mnew = fmaxf(mrow[rg], v);
      float alpha = expf(mrow[rg] - mnew);
      mrow[rg] = mnew;
      lrow[rg] *= alpha;
#pragma unroll
      for (int nt = 0; nt < 8; nt++) o[nt][rg] *= alpha;
      pmx[rg] = mnew;
    }
    // P = exp(s - m); write to LDS in A-fragment layout
    float ls[4] = {0.f, 0.f, 0.f, 0.f};
#pragma unroll
    for (int nt = 0; nt < 4; nt++)
#pragma unroll
      for (int rg = 0; rg < 4; rg++) {
        float p = expf(sv[nt][rg] - pmx[rg]);
        ls[rg] += p;
        Pls[wave][quad * 4 + rg][nt * 16 + l15] = (bf16)p;
      }
#pragma unroll
    for (int rg = 0; rg < 4; rg++) {
      float v = ls[rg];
      v += __shfl_xor(v, 1);
      v += __shfl_xor(v, 2);
      v += __shfl_xor(v, 4);
      v += __shfl_xor(v, 8);
      lrow[rg] += v;
    }
    __syncthreads();  // Pls write -> read

    // O += P @ V  (contraction over 64 k: 2 steps of 32)
    bf16x8 pf[2];
#pragma unroll
    for (int s2 = 0; s2 < 2; s2++)
      pf[s2] = *(const bf16x8*)&Pls[wave][l15][s2 * 32 + quad * 8];
#pragma unroll
    for (int nt = 0; nt < 8; nt++)
#pragma unroll
      for (int s2 = 0; s2 < 2; s2++) {
        bf16x8 vf = *(const bf16x8*)&Vls[nt * 16 + l15][s2 * 32 + quad * 8];
        o[nt] = __builtin_amdgcn_mfma_f32_16x16x32_bf16(pf[s2], vf, o[nt], 0, 0, 0);
      }
  }

  // finalize: O / l -> y[b, q, h*128 + d] bf16
#pragma unroll
  for (int rg = 0; rg < 4; rg++) {
    float inv = 1.0f / lrow[rg];
    int qg = qw0 + quad * 4 + rg;
    bf16* yr = y + ((size_t)b * LL + qg) * DD + h * HSS;
#pragma unroll
    for (int nt = 0; nt < 8; nt++) yr[nt * 16 + l15] = (bf16)(o[nt][rg] * inv);
  }
}

// ---------------------------------------------------------------------------
extern "C" void kernel_launch(void* const* d_in, const int* in_sizes, int n_in,
                              void* d_out, int out_size, void* d_ws, size_t ws_size,
                              hipStream_t stream) {
  const float* x = (const float*)d_in[0];
  const float* W_qkv = (const float*)d_in[1];
  const float* b_qkv = (const float*)d_in[2];
  const float* W_o = (const float*)d_in[3];
  const float* b_o = (const float*)d_in[4];
  const float* Er = (const float*)d_in[5];
  const float* ln1_g = (const float*)d_in[6];
  const float* ln1_b = (const float*)d_in[7];
  const float* ln2_g = (const float*)d_in[8];
  const float* ln2_b = (const float*)d_in[9];
  const float* W_fc = (const float*)d_in[10];
  const float* b_fc = (const float*)d_in[11];
  const float* W_proj = (const float*)d_in[12];
  const float* b_proj = (const float*)d_in[13];
  float* out = (float*)d_out;

  char* p = (char*)d_ws;
  auto alloc = [&](size_t bytes) {
    char* r = p;
    p += (bytes + 255) & ~(size_t)255;
    return r;
  };
  bf16* Wt_qkv = (bf16*)alloc((size_t)3072 * 1024 * 2);
  bf16* Wt_o   = (bf16*)alloc((size_t)1024 * 1024 * 2);
  bf16* Wt_fc  = (bf16*)alloc((size_t)4096 * 1024 * 2);
  bf16* Wt_pr  = (bf16*)alloc((size_t)1024 * 4096 * 2);
  bf16* Erb    = (bf16*)alloc((size_t)1024 * 128 * 2);
  bf16* xn     = (bf16*)alloc((size_t)8192 * 1024 * 2);
  bf16* qkvb   = (bf16*)alloc((size_t)8192 * 3072 * 2);  // also reused as hb
  bf16* yb     = (bf16*)alloc((size_t)8192 * 1024 * 2);
  float* x2    = (float*)alloc((size_t)8192 * 1024 * 4);
  bf16* hb     = qkvb;  // qkvb(50MB)+yb(16MB) dead after attn/out-proj; h needs 64MB

  // weight prep
  transpose_cast_kernel<<<dim3(3072 / 32, 1024 / 32), dim3(32, 8), 0, stream>>>(W_qkv, Wt_qkv, 1024, 3072);
  transpose_cast_kernel<<<dim3(1024 / 32, 1024 / 32), dim3(32, 8), 0, stream>>>(W_o, Wt_o, 1024, 1024);
  transpose_cast_kernel<<<dim3(4096 / 32, 1024 / 32), dim3(32, 8), 0, stream>>>(W_fc, Wt_fc, 1024, 4096);
  transpose_cast_kernel<<<dim3(1024 / 32, 4096 / 32), dim3(32, 8), 0, stream>>>(W_proj, Wt_pr, 4096, 1024);
  cast_bf16_kernel<<<512, 256, 0, stream>>>(Er, Erb, 1024 * 128);

  // block
  ln_kernel<<<8192, 256, 0, stream>>>(x, ln1_g, ln1_b, xn);
  gemm_kernel<0><<<dim3(24, 64), 256, 0, stream>>>(xn, Wt_qkv, b_qkv, nullptr, qkvb, 8192, 3072, 1024);
  flash_kernel<<<dim3(16, 8, 8), 256, 0, stream>>>(qkvb, Erb, yb);
  gemm_kernel<2><<<dim3(8, 64), 256, 0, stream>>>(yb, Wt_o, b_o, x, x2, 8192, 1024, 1024);
  ln_kernel<<<8192, 256, 0, stream>>>(x2, ln2_g, ln2_b, xn);
  gemm_kernel<1><<<dim3(32, 64), 256, 0, stream>>>(xn, Wt_fc, b_fc, nullptr, hb, 8192, 4096, 1024);
  gemm_kernel<2><<<dim3(8, 64), 256, 0, stream>>>(hb, Wt_pr, b_proj, x2, out, 8192, 1024, 4096);
}